// Round 4
// baseline (3217.950 us; speedup 1.0000x reference)
//
#include <hip/hip_runtime.h>
#include <math.h>

#define TT 12
#define FF 32
#define HH 64
#define OO 8
#define GG 256   // 4*HH
#define NF 4     // NUM_FUTURE
#define BR 16    // rows per lstm block
#define LDW 260  // padded LDS row stride (words): 256+4, keeps 16B align; rows rg+4r' -> banks {0,4,8,12}

__device__ __forceinline__ float sigmoidf_(float x){ return 1.f/(1.f+expf(-x)); }

// ================= CSR build =================
__global__ void hist_kernel(const int* __restrict__ dst, int* __restrict__ cnt, int E){
  int e = blockIdx.x*blockDim.x + threadIdx.x;
  if (e < E) atomicAdd(&cnt[dst[e]], 1);
}

__global__ __launch_bounds__(1024) void scan_kernel(const int* __restrict__ cnt,
                                                    int* __restrict__ ptr,
                                                    float* __restrict__ invd, int N){
  __shared__ int buf[1024];
  __shared__ int carry;
  if (threadIdx.x == 0) carry = 0;
  __syncthreads();
  for (int base = 0; base < N; base += 1024){
    int i = base + threadIdx.x;
    int v = (i < N) ? cnt[i] : 0;
    buf[threadIdx.x] = v;
    __syncthreads();
    for (int off = 1; off < 1024; off <<= 1){
      int t = (threadIdx.x >= off) ? buf[threadIdx.x - off] : 0;
      __syncthreads();
      buf[threadIdx.x] += t;
      __syncthreads();
    }
    int incl = buf[threadIdx.x];
    if (i < N){
      ptr[i] = carry + incl - v;
      invd[i] = 1.f / fmaxf((float)v, 1.f);
    }
    __syncthreads();
    if (threadIdx.x == 1023){
      carry += incl;
      if (base + 1024 >= N) ptr[N] = carry;
    }
    __syncthreads();
  }
}

// pack (src, w) into int2 for single-load edge metadata
__global__ void fill_kernel(const int* __restrict__ src, const int* __restrict__ dst,
                            const float* __restrict__ ew, const int* __restrict__ ptr,
                            int* __restrict__ fill, int2* __restrict__ csr_sw, int E){
  int e = blockIdx.x*blockDim.x + threadIdx.x;
  if (e >= E) return;
  int d = dst[e];
  int pos = ptr[d] + atomicAdd(&fill[d], 1);
  int2 m; m.x = src[e]; m.y = __float_as_int(ew[e]);
  csr_sw[pos] = m;
}

// ========== SAGE aggregation: t-inner (6 planes/lane), edge-unroll 2 ==========
__global__ __launch_bounds__(256) void sage_gather(
    const float* __restrict__ x, const int* __restrict__ ptr,
    const int2* __restrict__ csr_sw,
    const float* __restrict__ invd, float* __restrict__ aggx, int N){
  int wave = threadIdx.x >> 6, lane = threadIdx.x & 63;
  int f = lane & 31, tp = lane >> 5;
  int n = blockIdx.x*4 + wave;
  if (n >= N) return;
  int beg = ptr[n], end = ptr[n+1];
  float id = invd[n];
  float acc[TT/2];
  #pragma unroll
  for (int th = 0; th < TT/2; ++th) acc[th] = 0.f;
  const size_t plane = (size_t)N*FF;
  int e = beg;
  for (; e+2 <= end; e += 2){
    int2 m0 = csr_sw[e], m1 = csr_sw[e+1];
    const float* p0 = x + (size_t)m0.x*FF + f + (size_t)tp*plane;
    const float* p1 = x + (size_t)m1.x*FF + f + (size_t)tp*plane;
    float w0 = __int_as_float(m0.y), w1 = __int_as_float(m1.y);
    #pragma unroll
    for (int th = 0; th < TT/2; ++th)
      acc[th] += p0[2*th*plane]*w0 + p1[2*th*plane]*w1;
  }
  for (; e < end; ++e){
    int2 m = csr_sw[e];
    const float* p = x + (size_t)m.x*FF + f + (size_t)tp*plane;
    float wv = __int_as_float(m.y);
    #pragma unroll
    for (int th = 0; th < TT/2; ++th)
      acc[th] += p[2*th*plane]*wv;
  }
  #pragma unroll
  for (int th = 0; th < TT/2; ++th)
    aggx[(size_t)(2*th+tp)*plane + (size_t)n*FF + f] = acc[th] * id;  // pre-normalized
}

// ================= SAGE linear: emb = agg@Wr + x@Wroot + b ; xr = relu =====
__global__ __launch_bounds__(256) void sage_gemm(
    const float* __restrict__ x, const float* __restrict__ agg,
    const float* __restrict__ Wr, const float* __restrict__ Wroot,
    const float* __restrict__ b,
    float* __restrict__ emb, float* __restrict__ xr, int N){
  __shared__ float sWr[FF*HH], sWroot[FF*HH];
  for (int i = threadIdx.x; i < FF*HH; i += 256){ sWr[i] = Wr[i]; sWroot[i] = Wroot[i]; }
  __syncthreads();
  int idx = blockIdx.x*256 + threadIdx.x;
  int row = idx >> 6, hh = idx & (HH-1);
  if (row >= TT*N) return;
  const float* xv = x   + (size_t)row*FF;
  const float* av = agg + (size_t)row*FF;
  float acc = b[hh];
  #pragma unroll
  for (int k = 0; k < FF; ++k)
    acc += av[k]*sWr[k*HH+hh] + xv[k]*sWroot[k*HH+hh];
  emb[(size_t)row*HH + hh] = acc;
  xr[(size_t)row*HH + hh]  = fmaxf(acc, 0.f);
}

// ========== xr aggregation: t-inner (12 acc), edge-unroll 2 ==========
__global__ __launch_bounds__(256) void xr_gather(
    const float* __restrict__ xr, const int* __restrict__ ptr,
    const int2* __restrict__ csr_sw,
    const float* __restrict__ invd, float* __restrict__ xr_agg, int N){
  int wave = threadIdx.x >> 6, lane = threadIdx.x & 63;
  int n = blockIdx.x*4 + wave;
  if (n >= N) return;
  int beg = ptr[n], end = ptr[n+1];
  float id = invd[n];
  float acc[TT];
  #pragma unroll
  for (int t = 0; t < TT; ++t) acc[t] = 0.f;
  const size_t plane = (size_t)N*HH;
  int e = beg;
  for (; e+2 <= end; e += 2){
    int2 m0 = csr_sw[e], m1 = csr_sw[e+1];
    const float* p0 = xr + (size_t)m0.x*HH + lane;
    const float* p1 = xr + (size_t)m1.x*HH + lane;
    float w0 = __int_as_float(m0.y), w1 = __int_as_float(m1.y);
    #pragma unroll
    for (int t = 0; t < TT; ++t)
      acc[t] += p0[t*plane]*w0 + p1[t*plane]*w1;
  }
  for (; e < end; ++e){
    int2 m = csr_sw[e];
    const float* p = xr + (size_t)m.x*HH + lane;
    float wv = __int_as_float(m.y);
    #pragma unroll
    for (int t = 0; t < TT; ++t)
      acc[t] += p[t*plane]*wv;
  }
  #pragma unroll
  for (int t = 0; t < TT; ++t)
    xr_agg[(size_t)t*plane + (size_t)n*HH + lane] = acc[t] * id;  // pre-normalized
}

// ============ fused: h-gather + gates GEMM + LSTM cell, 16 nodes/block ======
// inp = [xr_agg(pre-norm), h_agg*invd, xr, h] ; gates = inp @ [Wr;Wroot] + b
// Phase B: wave w owns cols [64w,64w+64); lane = (rg=lane>>4 rows rg+4r', cg=lane&15 cols cg*4)
__global__ __launch_bounds__(256) void lstm_step(
    const float* __restrict__ xr_t, const float* __restrict__ xragg_t,
    const float* __restrict__ h_prev, float* __restrict__ h_next,
    float* __restrict__ c, const float* __restrict__ invd,
    const int* __restrict__ ptr, const int2* __restrict__ csr_sw,
    const float* __restrict__ Wr, const float* __restrict__ Wroot,
    const float* __restrict__ b,
    float* __restrict__ h2_store, int N){
  __shared__ float lds[BR][LDW];
  int tid = threadIdx.x, wave = tid >> 6, lane = tid & 63;
  int base = blockIdx.x * BR;

  // ---- Phase A: gather h_agg (unroll-8, 8 loads in flight) + stage inputs ----
  for (int r4 = 0; r4 < 4; ++r4){
    int r = wave*4 + r4;
    int n = base + r;
    if (n < N){
      float id = invd[n];
      int beg = ptr[n], end = ptr[n+1];
      float a0=0.f,a1=0.f,a2=0.f,a3=0.f,a4=0.f,a5=0.f,a6=0.f,a7=0.f;
      int e = beg;
      for (; e+8 <= end; e += 8){
        int2 m0=csr_sw[e+0], m1=csr_sw[e+1], m2=csr_sw[e+2], m3=csr_sw[e+3];
        int2 m4=csr_sw[e+4], m5=csr_sw[e+5], m6=csr_sw[e+6], m7=csr_sw[e+7];
        a0 += h_prev[(size_t)m0.x*HH+lane]*__int_as_float(m0.y);
        a1 += h_prev[(size_t)m1.x*HH+lane]*__int_as_float(m1.y);
        a2 += h_prev[(size_t)m2.x*HH+lane]*__int_as_float(m2.y);
        a3 += h_prev[(size_t)m3.x*HH+lane]*__int_as_float(m3.y);
        a4 += h_prev[(size_t)m4.x*HH+lane]*__int_as_float(m4.y);
        a5 += h_prev[(size_t)m5.x*HH+lane]*__int_as_float(m5.y);
        a6 += h_prev[(size_t)m6.x*HH+lane]*__int_as_float(m6.y);
        a7 += h_prev[(size_t)m7.x*HH+lane]*__int_as_float(m7.y);
      }
      for (; e < end; ++e){
        int2 m = csr_sw[e];
        a0 += h_prev[(size_t)m.x*HH+lane]*__int_as_float(m.y);
      }
      lds[r][ 64+lane] = (((a0+a1)+(a2+a3))+((a4+a5)+(a6+a7))) * id;
      lds[r][    lane] = xragg_t[(size_t)n*HH + lane];
      lds[r][128+lane] = xr_t   [(size_t)n*HH + lane];
      lds[r][192+lane] = h_prev [(size_t)n*HH + lane];
    } else {
      lds[r][lane] = lds[r][64+lane] = lds[r][128+lane] = lds[r][192+lane] = 0.f;
    }
  }
  __syncthreads();

  // ---- Phase B: GEMM; wave-local 64 cols, 4 rows x 4 cols per thread ----
  int cg = lane & 15, rg = lane >> 4;
  int j0 = wave*64 + cg*4;
  float acc[4][4];
  {
    float4 bv = *(const float4*)&b[j0];
    #pragma unroll
    for (int r = 0; r < 4; ++r){
      acc[r][0]=bv.x; acc[r][1]=bv.y; acc[r][2]=bv.z; acc[r][3]=bv.w;
    }
  }
  #pragma unroll 4
  for (int k = 0; k < 128; k += 4){
    float4 w0 = *(const float4*)&Wr[(size_t)(k+0)*GG + j0];
    float4 w1 = *(const float4*)&Wr[(size_t)(k+1)*GG + j0];
    float4 w2 = *(const float4*)&Wr[(size_t)(k+2)*GG + j0];
    float4 w3 = *(const float4*)&Wr[(size_t)(k+3)*GG + j0];
    #pragma unroll
    for (int rp = 0; rp < 4; ++rp){
      float4 a = *(const float4*)&lds[rg + 4*rp][k];
      acc[rp][0] += a.x*w0.x + a.y*w1.x + a.z*w2.x + a.w*w3.x;
      acc[rp][1] += a.x*w0.y + a.y*w1.y + a.z*w2.y + a.w*w3.y;
      acc[rp][2] += a.x*w0.z + a.y*w1.z + a.z*w2.z + a.w*w3.z;
      acc[rp][3] += a.x*w0.w + a.y*w1.w + a.z*w2.w + a.w*w3.w;
    }
  }
  #pragma unroll 4
  for (int k = 0; k < 128; k += 4){
    float4 w0 = *(const float4*)&Wroot[(size_t)(k+0)*GG + j0];
    float4 w1 = *(const float4*)&Wroot[(size_t)(k+1)*GG + j0];
    float4 w2 = *(const float4*)&Wroot[(size_t)(k+2)*GG + j0];
    float4 w3 = *(const float4*)&Wroot[(size_t)(k+3)*GG + j0];
    #pragma unroll
    for (int rp = 0; rp < 4; ++rp){
      float4 a = *(const float4*)&lds[rg + 4*rp][128+k];
      acc[rp][0] += a.x*w0.x + a.y*w1.x + a.z*w2.x + a.w*w3.x;
      acc[rp][1] += a.x*w0.y + a.y*w1.y + a.z*w2.y + a.w*w3.y;
      acc[rp][2] += a.x*w0.z + a.y*w1.z + a.z*w2.z + a.w*w3.z;
      acc[rp][3] += a.x*w0.w + a.y*w1.w + a.z*w2.w + a.w*w3.w;
    }
  }
  __syncthreads();                      // done reading A-tile
  #pragma unroll
  for (int rp = 0; rp < 4; ++rp){
    float4 g4; g4.x=acc[rp][0]; g4.y=acc[rp][1]; g4.z=acc[rp][2]; g4.w=acc[rp][3];
    *(float4*)&lds[rg + 4*rp][j0] = g4;    // gates
  }
  __syncthreads();

  // ---- Phase C: cell update ----
  for (int r = wave; r < BR; r += 4){
    int n = base + r;
    if (n >= N) continue;
    float gi = lds[r][lane], gf = lds[r][64+lane], gg2 = lds[r][128+lane], go = lds[r][192+lane];
    float cn = sigmoidf_(gf)*c[(size_t)n*HH+lane] + sigmoidf_(gi)*tanhf(gg2);
    float hn = sigmoidf_(go)*tanhf(cn);
    c[(size_t)n*HH+lane] = cn;
    h_next[(size_t)n*HH+lane] = hn;
    if (h2_store) h2_store[(size_t)n*HH+lane] = hn;
  }
}

// ================= output head =================
__global__ void out_gemm(const float* __restrict__ xr8, const float* __restrict__ h2s,
                         const float* __restrict__ Wout, const float* __restrict__ bout,
                         float* __restrict__ out, int N){
  int idx = blockIdx.x*blockDim.x + threadIdx.x;
  if (idx >= NF*N*OO) return;
  int o = idx & (OO-1);
  int row = idx >> 3;                     // tt*N + n
  const float* xv = xr8 + (size_t)row*HH;
  const float* hv = h2s + (size_t)row*HH;
  float acc = bout[o];
  #pragma unroll
  for (int k = 0; k < HH; ++k)
    acc += xv[k]*Wout[k*OO+o] + hv[k]*Wout[(HH+k)*OO+o];
  out[idx] = acc;
}

__global__ void copyk(const float* __restrict__ s, float* __restrict__ d, int n){
  int i = blockIdx.x*blockDim.x + threadIdx.x;
  if (i < n) d[i] = s[i];
}

extern "C" void kernel_launch(void* const* d_in, const int* in_sizes, int n_in,
                              void* d_out, int out_size, void* d_ws, size_t ws_size,
                              hipStream_t stream){
  const float* x      = (const float*)d_in[0];
  const int*   ei     = (const int*)  d_in[1];
  const float* ew     = (const float*)d_in[2];
  const float* sWr    = (const float*)d_in[3];
  const float* sWroot = (const float*)d_in[4];
  const float* sb     = (const float*)d_in[5];
  const float* l1Wr   = (const float*)d_in[6];
  const float* l1Wroot= (const float*)d_in[7];
  const float* l1b    = (const float*)d_in[8];
  const float* l2Wr   = (const float*)d_in[9];
  const float* l2Wroot= (const float*)d_in[10];
  const float* l2b    = (const float*)d_in[11];
  const float* Wout   = (const float*)d_in[12];
  const float* bout   = (const float*)d_in[13];

  const int E = in_sizes[2];
  const int N = in_sizes[0] / (TT*FF);
  const int* src = ei;
  const int* dst = ei + E;

  float* out0   = (float*)d_out;              // [4,N,8]
  float* c2out  = out0 + (size_t)NF*N*OO;     // [N,64]
  float* embout = c2out + (size_t)N*HH;       // [12,N,64]

  float* w = (float*)d_ws;
  float* xr     = w;  w += (size_t)TT*N*HH;
  float* xr_agg = w;  w += (size_t)TT*N*HH;
  float* agg_x  = xr_agg;                     // alias: dead before xr_agg written
  float* hA     = w;  w += (size_t)N*HH;
  float* hB     = w;  w += (size_t)N*HH;
  float* cbuf   = w;  w += (size_t)N*HH;
  float* h2s    = w;  w += (size_t)NF*N*HH;
  float* invd   = w;  w += N;
  int*   cnt    = (int*)w;  w += N;
  int*   fill   = (int*)w;  w += N;
  int*   ptr    = (int*)w;  w += (N+2);       // keep int2 array 8B-aligned
  int2*  csr_sw = (int2*)w; w += (size_t)2*E;

  hipMemsetAsync(cnt,  0, (size_t)N*4, stream);
  hipMemsetAsync(fill, 0, (size_t)N*4, stream);
  hipMemsetAsync(hA,   0, (size_t)N*HH*4, stream);  // h0
  hipMemsetAsync(cbuf, 0, (size_t)N*HH*4, stream);  // c0

  hist_kernel<<<(E+255)/256, 256, 0, stream>>>(dst, cnt, E);
  scan_kernel<<<1, 1024, 0, stream>>>(cnt, ptr, invd, N);
  fill_kernel<<<(E+255)/256, 256, 0, stream>>>(src, dst, ew, ptr, fill, csr_sw, E);

  sage_gather<<<(N+3)/4, 256, 0, stream>>>(x, ptr, csr_sw, invd, agg_x, N);
  sage_gemm<<<((size_t)TT*N*HH+255)/256, 256, 0, stream>>>(x, agg_x, sWr, sWroot, sb,
                                                           embout, xr, N);
  xr_gather<<<(N+3)/4, 256, 0, stream>>>(xr, ptr, csr_sw, invd, xr_agg, N);

  const int stepBlocks = (N+BR-1)/BR;
  float* hp = hA; float* hn = hB;
  // LSTM1
  for (int t = 0; t < TT; ++t){
    lstm_step<<<stepBlocks, 256, 0, stream>>>(xr + (size_t)t*N*HH, xr_agg + (size_t)t*N*HH,
                                              hp, hn, cbuf, invd, ptr, csr_sw,
                                              l1Wr, l1Wroot, l1b, nullptr, N);
    float* tmp = hp; hp = hn; hn = tmp;
  }
  // LSTM2 (continues from h1[-1], c1)
  for (int t = 0; t < TT; ++t){
    float* store = (t >= TT-NF) ? (h2s + (size_t)(t-(TT-NF))*N*HH) : nullptr;
    lstm_step<<<stepBlocks, 256, 0, stream>>>(xr + (size_t)t*N*HH, xr_agg + (size_t)t*N*HH,
                                              hp, hn, cbuf, invd, ptr, csr_sw,
                                              l2Wr, l2Wroot, l2b, store, N);
    float* tmp = hp; hp = hn; hn = tmp;
  }

  out_gemm<<<((size_t)NF*N*OO+255)/256, 256, 0, stream>>>(xr + (size_t)(TT-NF)*N*HH, h2s,
                                                          Wout, bout, out0, N);
  copyk<<<((size_t)N*HH+255)/256, 256, 0, stream>>>(cbuf, c2out, N*HH);
}

// Round 5
// 3080.988 us; speedup vs baseline: 1.0445x; 1.0445x over previous
//
#include <hip/hip_runtime.h>
#include <math.h>

#define TT 12
#define FF 32
#define HH 64
#define OO 8
#define GG 256   // 4*HH
#define NF 4     // NUM_FUTURE
#define BR 16    // rows per gates block
#define LDW 260  // padded LDS row stride (words); rows rg+4r' -> banks {0,4,8,12}

__device__ __forceinline__ float sigmoidf_(float x){ return 1.f/(1.f+expf(-x)); }

// ================= CSR build =================
__global__ void hist_kernel(const int* __restrict__ dst, int* __restrict__ cnt, int E){
  int e = blockIdx.x*blockDim.x + threadIdx.x;
  if (e < E) atomicAdd(&cnt[dst[e]], 1);
}

__global__ __launch_bounds__(1024) void scan_kernel(const int* __restrict__ cnt,
                                                    int* __restrict__ ptr,
                                                    float* __restrict__ invd, int N){
  __shared__ int buf[1024];
  __shared__ int carry;
  if (threadIdx.x == 0) carry = 0;
  __syncthreads();
  for (int base = 0; base < N; base += 1024){
    int i = base + threadIdx.x;
    int v = (i < N) ? cnt[i] : 0;
    buf[threadIdx.x] = v;
    __syncthreads();
    for (int off = 1; off < 1024; off <<= 1){
      int t = (threadIdx.x >= off) ? buf[threadIdx.x - off] : 0;
      __syncthreads();
      buf[threadIdx.x] += t;
      __syncthreads();
    }
    int incl = buf[threadIdx.x];
    if (i < N){
      ptr[i] = carry + incl - v;
      invd[i] = 1.f / fmaxf((float)v, 1.f);
    }
    __syncthreads();
    if (threadIdx.x == 1023){
      carry += incl;
      if (base + 1024 >= N) ptr[N] = carry;
    }
    __syncthreads();
  }
}

__global__ void fill_kernel(const int* __restrict__ src, const int* __restrict__ dst,
                            const float* __restrict__ ew, const int* __restrict__ ptr,
                            int* __restrict__ fill, int2* __restrict__ csr_sw, int E){
  int e = blockIdx.x*blockDim.x + threadIdx.x;
  if (e >= E) return;
  int d = dst[e];
  int pos = ptr[d] + atomicAdd(&fill[d], 1);
  int2 m; m.x = src[e]; m.y = __float_as_int(ew[e]);
  csr_sw[pos] = m;
}

// ========== SAGE aggregation: t-inner (6 planes/lane), edge-unroll 2 ==========
__global__ __launch_bounds__(256) void sage_gather(
    const float* __restrict__ x, const int* __restrict__ ptr,
    const int2* __restrict__ csr_sw,
    const float* __restrict__ invd, float* __restrict__ aggx, int N){
  int wave = threadIdx.x >> 6, lane = threadIdx.x & 63;
  int f = lane & 31, tp = lane >> 5;
  int n = blockIdx.x*4 + wave;
  if (n >= N) return;
  int beg = ptr[n], end = ptr[n+1];
  float id = invd[n];
  float acc[TT/2];
  #pragma unroll
  for (int th = 0; th < TT/2; ++th) acc[th] = 0.f;
  const size_t plane = (size_t)N*FF;
  int e = beg;
  for (; e+2 <= end; e += 2){
    int2 m0 = csr_sw[e], m1 = csr_sw[e+1];
    const float* p0 = x + (size_t)m0.x*FF + f + (size_t)tp*plane;
    const float* p1 = x + (size_t)m1.x*FF + f + (size_t)tp*plane;
    float w0 = __int_as_float(m0.y), w1 = __int_as_float(m1.y);
    #pragma unroll
    for (int th = 0; th < TT/2; ++th)
      acc[th] += p0[2*th*plane]*w0 + p1[2*th*plane]*w1;
  }
  for (; e < end; ++e){
    int2 m = csr_sw[e];
    const float* p = x + (size_t)m.x*FF + f + (size_t)tp*plane;
    float wv = __int_as_float(m.y);
    #pragma unroll
    for (int th = 0; th < TT/2; ++th)
      acc[th] += p[2*th*plane]*wv;
  }
  #pragma unroll
  for (int th = 0; th < TT/2; ++th)
    aggx[(size_t)(2*th+tp)*plane + (size_t)n*FF + f] = acc[th] * id;  // pre-normalized
}

// ================= SAGE linear: emb = agg@Wr + x@Wroot + b ; xr = relu =====
__global__ __launch_bounds__(256) void sage_gemm(
    const float* __restrict__ x, const float* __restrict__ agg,
    const float* __restrict__ Wr, const float* __restrict__ Wroot,
    const float* __restrict__ b,
    float* __restrict__ emb, float* __restrict__ xr, int N){
  __shared__ float sWr[FF*HH], sWroot[FF*HH];
  for (int i = threadIdx.x; i < FF*HH; i += 256){ sWr[i] = Wr[i]; sWroot[i] = Wroot[i]; }
  __syncthreads();
  int idx = blockIdx.x*256 + threadIdx.x;
  int row = idx >> 6, hh = idx & (HH-1);
  if (row >= TT*N) return;
  const float* xv = x   + (size_t)row*FF;
  const float* av = agg + (size_t)row*FF;
  float acc = b[hh];
  #pragma unroll
  for (int k = 0; k < FF; ++k)
    acc += av[k]*sWr[k*HH+hh] + xv[k]*sWroot[k*HH+hh];
  emb[(size_t)row*HH + hh] = acc;
  xr[(size_t)row*HH + hh]  = fmaxf(acc, 0.f);
}

// ========== xr aggregation: t-inner (12 acc), edge-unroll 2 ==========
__global__ __launch_bounds__(256) void xr_gather(
    const float* __restrict__ xr, const int* __restrict__ ptr,
    const int2* __restrict__ csr_sw,
    const float* __restrict__ invd, float* __restrict__ xr_agg, int N){
  int wave = threadIdx.x >> 6, lane = threadIdx.x & 63;
  int n = blockIdx.x*4 + wave;
  if (n >= N) return;
  int beg = ptr[n], end = ptr[n+1];
  float id = invd[n];
  float acc[TT];
  #pragma unroll
  for (int t = 0; t < TT; ++t) acc[t] = 0.f;
  const size_t plane = (size_t)N*HH;
  int e = beg;
  for (; e+2 <= end; e += 2){
    int2 m0 = csr_sw[e], m1 = csr_sw[e+1];
    const float* p0 = xr + (size_t)m0.x*HH + lane;
    const float* p1 = xr + (size_t)m1.x*HH + lane;
    float w0 = __int_as_float(m0.y), w1 = __int_as_float(m1.y);
    #pragma unroll
    for (int t = 0; t < TT; ++t)
      acc[t] += p0[t*plane]*w0 + p1[t*plane]*w1;
  }
  for (; e < end; ++e){
    int2 m = csr_sw[e];
    const float* p = xr + (size_t)m.x*HH + lane;
    float wv = __int_as_float(m.y);
    #pragma unroll
    for (int t = 0; t < TT; ++t)
      acc[t] += p[t*plane]*wv;
  }
  #pragma unroll
  for (int t = 0; t < TT; ++t)
    xr_agg[(size_t)t*plane + (size_t)n*HH + lane] = acc[t] * id;  // pre-normalized
}

// ============ per-step h aggregation: one wave per node, gather ============
__global__ __launch_bounds__(256) void hgather_step(
    const float* __restrict__ h_prev, const int* __restrict__ ptr,
    const int2* __restrict__ csr_sw, const float* __restrict__ invd,
    float* __restrict__ h_agg, int N){
  int wave = threadIdx.x >> 6, lane = threadIdx.x & 63;
  int n = blockIdx.x*4 + wave;
  if (n >= N) return;
  int beg = ptr[n], end = ptr[n+1];
  float a0=0.f,a1=0.f,a2=0.f,a3=0.f,a4=0.f,a5=0.f,a6=0.f,a7=0.f;
  int e = beg;
  for (; e+8 <= end; e += 8){
    int2 m0=csr_sw[e+0], m1=csr_sw[e+1], m2=csr_sw[e+2], m3=csr_sw[e+3];
    int2 m4=csr_sw[e+4], m5=csr_sw[e+5], m6=csr_sw[e+6], m7=csr_sw[e+7];
    a0 += h_prev[(size_t)m0.x*HH+lane]*__int_as_float(m0.y);
    a1 += h_prev[(size_t)m1.x*HH+lane]*__int_as_float(m1.y);
    a2 += h_prev[(size_t)m2.x*HH+lane]*__int_as_float(m2.y);
    a3 += h_prev[(size_t)m3.x*HH+lane]*__int_as_float(m3.y);
    a4 += h_prev[(size_t)m4.x*HH+lane]*__int_as_float(m4.y);
    a5 += h_prev[(size_t)m5.x*HH+lane]*__int_as_float(m5.y);
    a6 += h_prev[(size_t)m6.x*HH+lane]*__int_as_float(m6.y);
    a7 += h_prev[(size_t)m7.x*HH+lane]*__int_as_float(m7.y);
  }
  for (; e < end; ++e){
    int2 m = csr_sw[e];
    a0 += h_prev[(size_t)m.x*HH+lane]*__int_as_float(m.y);
  }
  h_agg[(size_t)n*HH+lane] = (((a0+a1)+(a2+a3))+((a4+a5)+(a6+a7))) * invd[n];  // pre-normalized
}

// ============ gates GEMM + LSTM cell, BR nodes/block ======
// inp = [xr_agg, h_agg, xr, h] (aggs pre-normalized); gates = inp @ [Wr;Wroot] + b
__global__ __launch_bounds__(256) void gates_cell_step(
    const float* __restrict__ xr_t, const float* __restrict__ xragg_t,
    const float* __restrict__ h_agg,
    const float* __restrict__ h_prev, float* __restrict__ h_next,
    float* __restrict__ c,
    const float* __restrict__ Wr, const float* __restrict__ Wroot,
    const float* __restrict__ b,
    float* __restrict__ h2_store, int N){
  __shared__ float lds[BR][LDW];
  int tid = threadIdx.x, wave = tid >> 6, lane = tid & 63;
  int base = blockIdx.x * BR;

  // ---- stage inputs: row r, col tid; waves read 4 distinct coalesced streams ----
  for (int r = 0; r < BR; ++r){
    int n = base + r;
    int k = tid;
    float v;
    if (n < N){
      if      (k < 64)  v = xragg_t[(size_t)n*HH + k];
      else if (k < 128) v = h_agg  [(size_t)n*HH + (k-64)];
      else if (k < 192) v = xr_t   [(size_t)n*HH + (k-128)];
      else              v = h_prev [(size_t)n*HH + (k-192)];
    } else v = 0.f;
    lds[r][k] = v;
  }
  __syncthreads();

  // ---- GEMM: wave owns cols [64w,64w+64); 4 rows x 4 cols per thread ----
  int cg = lane & 15, rg = lane >> 4;
  int j0 = wave*64 + cg*4;
  float acc[4][4];
  {
    float4 bv = *(const float4*)&b[j0];
    #pragma unroll
    for (int r = 0; r < 4; ++r){
      acc[r][0]=bv.x; acc[r][1]=bv.y; acc[r][2]=bv.z; acc[r][3]=bv.w;
    }
  }
  #pragma unroll 4
  for (int k = 0; k < 128; k += 4){
    float4 w0 = *(const float4*)&Wr[(size_t)(k+0)*GG + j0];
    float4 w1 = *(const float4*)&Wr[(size_t)(k+1)*GG + j0];
    float4 w2 = *(const float4*)&Wr[(size_t)(k+2)*GG + j0];
    float4 w3 = *(const float4*)&Wr[(size_t)(k+3)*GG + j0];
    #pragma unroll
    for (int rp = 0; rp < 4; ++rp){
      float4 a = *(const float4*)&lds[rg + 4*rp][k];
      acc[rp][0] += a.x*w0.x + a.y*w1.x + a.z*w2.x + a.w*w3.x;
      acc[rp][1] += a.x*w0.y + a.y*w1.y + a.z*w2.y + a.w*w3.y;
      acc[rp][2] += a.x*w0.z + a.y*w1.z + a.z*w2.z + a.w*w3.z;
      acc[rp][3] += a.x*w0.w + a.y*w1.w + a.z*w2.w + a.w*w3.w;
    }
  }
  #pragma unroll 4
  for (int k = 0; k < 128; k += 4){
    float4 w0 = *(const float4*)&Wroot[(size_t)(k+0)*GG + j0];
    float4 w1 = *(const float4*)&Wroot[(size_t)(k+1)*GG + j0];
    float4 w2 = *(const float4*)&Wroot[(size_t)(k+2)*GG + j0];
    float4 w3 = *(const float4*)&Wroot[(size_t)(k+3)*GG + j0];
    #pragma unroll
    for (int rp = 0; rp < 4; ++rp){
      float4 a = *(const float4*)&lds[rg + 4*rp][128+k];
      acc[rp][0] += a.x*w0.x + a.y*w1.x + a.z*w2.x + a.w*w3.x;
      acc[rp][1] += a.x*w0.y + a.y*w1.y + a.z*w2.y + a.w*w3.y;
      acc[rp][2] += a.x*w0.z + a.y*w1.z + a.z*w2.z + a.w*w3.z;
      acc[rp][3] += a.x*w0.w + a.y*w1.w + a.z*w2.w + a.w*w3.w;
    }
  }
  __syncthreads();
  #pragma unroll
  for (int rp = 0; rp < 4; ++rp){
    float4 g4; g4.x=acc[rp][0]; g4.y=acc[rp][1]; g4.z=acc[rp][2]; g4.w=acc[rp][3];
    *(float4*)&lds[rg + 4*rp][j0] = g4;    // gates
  }
  __syncthreads();

  // ---- cell update ----
  for (int r = wave; r < BR; r += 4){
    int n = base + r;
    if (n >= N) continue;
    float gi = lds[r][lane], gf = lds[r][64+lane], gg2 = lds[r][128+lane], go = lds[r][192+lane];
    float cn = sigmoidf_(gf)*c[(size_t)n*HH+lane] + sigmoidf_(gi)*tanhf(gg2);
    float hn = sigmoidf_(go)*tanhf(cn);
    c[(size_t)n*HH+lane] = cn;
    h_next[(size_t)n*HH+lane] = hn;
    if (h2_store) h2_store[(size_t)n*HH+lane] = hn;
  }
}

// ================= output head =================
__global__ void out_gemm(const float* __restrict__ xr8, const float* __restrict__ h2s,
                         const float* __restrict__ Wout, const float* __restrict__ bout,
                         float* __restrict__ out, int N){
  int idx = blockIdx.x*blockDim.x + threadIdx.x;
  if (idx >= NF*N*OO) return;
  int o = idx & (OO-1);
  int row = idx >> 3;                     // tt*N + n
  const float* xv = xr8 + (size_t)row*HH;
  const float* hv = h2s + (size_t)row*HH;
  float acc = bout[o];
  #pragma unroll
  for (int k = 0; k < HH; ++k)
    acc += xv[k]*Wout[k*OO+o] + hv[k]*Wout[(HH+k)*OO+o];
  out[idx] = acc;
}

__global__ void copyk(const float* __restrict__ s, float* __restrict__ d, int n){
  int i = blockIdx.x*blockDim.x + threadIdx.x;
  if (i < n) d[i] = s[i];
}

extern "C" void kernel_launch(void* const* d_in, const int* in_sizes, int n_in,
                              void* d_out, int out_size, void* d_ws, size_t ws_size,
                              hipStream_t stream){
  const float* x      = (const float*)d_in[0];
  const int*   ei     = (const int*)  d_in[1];
  const float* ew     = (const float*)d_in[2];
  const float* sWr    = (const float*)d_in[3];
  const float* sWroot = (const float*)d_in[4];
  const float* sb     = (const float*)d_in[5];
  const float* l1Wr   = (const float*)d_in[6];
  const float* l1Wroot= (const float*)d_in[7];
  const float* l1b    = (const float*)d_in[8];
  const float* l2Wr   = (const float*)d_in[9];
  const float* l2Wroot= (const float*)d_in[10];
  const float* l2b    = (const float*)d_in[11];
  const float* Wout   = (const float*)d_in[12];
  const float* bout   = (const float*)d_in[13];

  const int E = in_sizes[2];
  const int N = in_sizes[0] / (TT*FF);
  const int* src = ei;
  const int* dst = ei + E;

  float* out0   = (float*)d_out;              // [4,N,8]
  float* c2out  = out0 + (size_t)NF*N*OO;     // [N,64]
  float* embout = c2out + (size_t)N*HH;       // [12,N,64]

  float* w = (float*)d_ws;
  float* xr     = w;  w += (size_t)TT*N*HH;
  float* xr_agg = w;  w += (size_t)TT*N*HH;
  float* agg_x  = xr_agg;                     // alias: dead before xr_agg written
  float* hA     = w;  w += (size_t)N*HH;
  float* hB     = w;  w += (size_t)N*HH;
  float* cbuf   = w;  w += (size_t)N*HH;
  float* haggb  = w;  w += (size_t)N*HH;
  float* h2s    = w;  w += (size_t)NF*N*HH;
  float* invd   = w;  w += N;
  int*   cnt    = (int*)w;  w += N;
  int*   fill   = (int*)w;  w += N;
  int*   ptr    = (int*)w;  w += (N+2);       // keep int2 array 8B-aligned
  int2*  csr_sw = (int2*)w; w += (size_t)2*E;

  hipMemsetAsync(cnt,  0, (size_t)N*4, stream);
  hipMemsetAsync(fill, 0, (size_t)N*4, stream);
  hipMemsetAsync(hA,   0, (size_t)N*HH*4, stream);  // h0
  hipMemsetAsync(cbuf, 0, (size_t)N*HH*4, stream);  // c0

  hist_kernel<<<(E+255)/256, 256, 0, stream>>>(dst, cnt, E);
  scan_kernel<<<1, 1024, 0, stream>>>(cnt, ptr, invd, N);
  fill_kernel<<<(E+255)/256, 256, 0, stream>>>(src, dst, ew, ptr, fill, csr_sw, E);

  sage_gather<<<(N+3)/4, 256, 0, stream>>>(x, ptr, csr_sw, invd, agg_x, N);
  sage_gemm<<<((size_t)TT*N*HH+255)/256, 256, 0, stream>>>(x, agg_x, sWr, sWroot, sb,
                                                           embout, xr, N);
  xr_gather<<<(N+3)/4, 256, 0, stream>>>(xr, ptr, csr_sw, invd, xr_agg, N);

  const int gBlocks = (N+3)/4;          // hgather: one wave per node
  const int sBlocks = (N+BR-1)/BR;      // gates: BR nodes per block
  float* hp = hA; float* hn = hB;
  // LSTM1
  for (int t = 0; t < TT; ++t){
    hgather_step<<<gBlocks, 256, 0, stream>>>(hp, ptr, csr_sw, invd, haggb, N);
    gates_cell_step<<<sBlocks, 256, 0, stream>>>(xr + (size_t)t*N*HH, xr_agg + (size_t)t*N*HH,
                                                 haggb, hp, hn, cbuf,
                                                 l1Wr, l1Wroot, l1b, nullptr, N);
    float* tmp = hp; hp = hn; hn = tmp;
  }
  // LSTM2 (continues from h1[-1], c1)
  for (int t = 0; t < TT; ++t){
    float* store = (t >= TT-NF) ? (h2s + (size_t)(t-(TT-NF))*N*HH) : nullptr;
    hgather_step<<<gBlocks, 256, 0, stream>>>(hp, ptr, csr_sw, invd, haggb, N);
    gates_cell_step<<<sBlocks, 256, 0, stream>>>(xr + (size_t)t*N*HH, xr_agg + (size_t)t*N*HH,
                                                 haggb, hp, hn, cbuf,
                                                 l2Wr, l2Wroot, l2b, store, N);
    float* tmp = hp; hp = hn; hn = tmp;
  }

  out_gemm<<<((size_t)NF*N*OO+255)/256, 256, 0, stream>>>(xr + (size_t)(TT-NF)*N*HH, h2s,
                                                          Wout, bout, out0, N);
  copyk<<<((size_t)N*HH+255)/256, 256, 0, stream>>>(cbuf, c2out, N*HH);
}